// Round 2
// baseline (405.965 us; speedup 1.0000x reference)
//
#include <hip/hip_runtime.h>

// B=8, C=64, H=256, W=512, 3x3 spherical taps, O=1, 2x2 upsample -> (8,1,512,1024) fp32.
#define Bn   8
#define Cn   64
#define Hn   256
#define Wn   512
#define HWn  (Hn * Wn)
#define TAPS 9

// ---------------------------------------------------------------------------
// Pass 0: transpose gather indices. off9[k][p] = gi*W + gj  (p = h*W+w).
// One-time 9.4 MB stride-9 read, 4.7 MB coalesced write.
// ---------------------------------------------------------------------------
__global__ __launch_bounds__(256) void pass0_idx(
    const int* __restrict__ gi, const int* __restrict__ gj,
    int* __restrict__ off9)
{
    int p = blockIdx.x * 256 + threadIdx.x;   // 0..HW-1
    int base = p * TAPS;
#pragma unroll
    for (int k = 0; k < TAPS; ++k)
        off9[k * HWn + p] = gi[base + k] * Wn + gj[base + k];
}

// ---------------------------------------------------------------------------
// Pass 1: channel-dot, batch-innermost output layout.
//   D[k][p][b] = sum_c feat[b][c][p] * wt[c][k]
// Thread per pixel p; lanes = consecutive x -> every feature load is a
// coalesced 256 B dword stream; weights staged in LDS (broadcast reads).
// Each tap's 8 batch values are stored as two contiguous float4 (32 B/lane).
// ---------------------------------------------------------------------------
__global__ __launch_bounds__(256) void pass1_chandot(
    const float* __restrict__ feat, const float* __restrict__ wt,
    float* __restrict__ D)
{
    __shared__ float wl[Cn * TAPS];
    for (int i = threadIdx.x; i < Cn * TAPS; i += 256) wl[i] = wt[i];
    __syncthreads();

    int p = blockIdx.x * 256 + threadIdx.x;   // 0..HW-1

    float acc[TAPS][Bn];
#pragma unroll
    for (int k = 0; k < TAPS; ++k)
#pragma unroll
        for (int b = 0; b < Bn; ++b) acc[k][b] = 0.f;

#pragma unroll 2
    for (int c = 0; c < Cn; ++c) {
        float f[Bn];
#pragma unroll
        for (int b = 0; b < Bn; ++b)
            f[b] = feat[((size_t)b * Cn + c) * HWn + p];
#pragma unroll
        for (int k = 0; k < TAPS; ++k) {
            float wv = wl[c * TAPS + k];
#pragma unroll
            for (int b = 0; b < Bn; ++b)
                acc[k][b] = fmaf(f[b], wv, acc[k][b]);
        }
    }

#pragma unroll
    for (int k = 0; k < TAPS; ++k) {
        float4* dst = (float4*)(D + ((size_t)k * HWn + p) * Bn);
        dst[0] = make_float4(acc[k][0], acc[k][1], acc[k][2], acc[k][3]);
        dst[1] = make_float4(acc[k][4], acc[k][5], acc[k][6], acc[k][7]);
    }
}

// ---------------------------------------------------------------------------
// Pass 2: gather 9 taps (all 8 batches at once: 2x float4 = 32 B contiguous
// per lane), sum, write the 2x2-upsampled output for all 8 batches.
// Index reads are lane-coalesced thanks to pass0's transpose.
// ---------------------------------------------------------------------------
__global__ __launch_bounds__(256) void pass2_gather(
    const float* __restrict__ D, const int* __restrict__ off9,
    float* __restrict__ out)
{
    int p = blockIdx.x * 256 + threadIdx.x;   // 0..HW-1
    int w = p & (Wn - 1);
    int h = p >> 9;

    float4 a0 = make_float4(0.f, 0.f, 0.f, 0.f);
    float4 a1 = make_float4(0.f, 0.f, 0.f, 0.f);
#pragma unroll
    for (int k = 0; k < TAPS; ++k) {
        int off = off9[k * HWn + p];
        const float4* d = (const float4*)(D + ((size_t)k * HWn + off) * Bn);
        float4 d0 = d[0], d1 = d[1];
        a0.x += d0.x; a0.y += d0.y; a0.z += d0.z; a0.w += d0.w;
        a1.x += d1.x; a1.y += d1.y; a1.z += d1.z; a1.w += d1.w;
    }

    float vals[Bn] = {a0.x, a0.y, a0.z, a0.w, a1.x, a1.y, a1.z, a1.w};
#pragma unroll
    for (int b = 0; b < Bn; ++b) {
        float2 vv = make_float2(vals[b], vals[b]);
        size_t o = ((size_t)b * (2 * Hn) + 2 * h) * (size_t)(2 * Wn) + 2 * w;
        *(float2*)(out + o)            = vv;
        *(float2*)(out + o + 2 * Wn)   = vv;
    }
}

// ---------------------------------------------------------------------------
// Fallback (ws too small): direct per-pixel 9x64 gather-dot.
// ---------------------------------------------------------------------------
__global__ __launch_bounds__(256) void direct_kernel(
    const float* __restrict__ feat, const float* __restrict__ wt,
    const int* __restrict__ gi, const int* __restrict__ gj,
    float* __restrict__ out)
{
    int p = blockIdx.x * blockDim.x + threadIdx.x;
    int w = p & (Wn - 1);
    int h = (p >> 9) & (Hn - 1);
    int b = p >> 17;

    int iidx = ((h << 9) | w) * TAPS;
    int off[TAPS];
#pragma unroll
    for (int k = 0; k < TAPS; ++k)
        off[k] = gi[iidx + k] * Wn + gj[iidx + k];

    float acc = 0.f;
    for (int c = 0; c < Cn; ++c) {
        const float* fc = feat + ((size_t)b * Cn + c) * HWn;
#pragma unroll
        for (int k = 0; k < TAPS; ++k)
            acc = fmaf(fc[off[k]], wt[c * TAPS + k], acc);
    }

    float2 v = make_float2(acc, acc);
    size_t o0 = ((size_t)b * (2 * Hn) + 2 * h) * (size_t)(2 * Wn) + 2 * w;
    *(float2*)(out + o0)          = v;
    *(float2*)(out + o0 + 2 * Wn) = v;
}

extern "C" void kernel_launch(void* const* d_in, const int* in_sizes, int n_in,
                              void* d_out, int out_size, void* d_ws, size_t ws_size,
                              hipStream_t stream) {
    const float* feat = (const float*)d_in[0];   // [8,64,256,512] fp32
    const float* wt   = (const float*)d_in[1];   // [1,64,3,3]     fp32
    const int*   gi   = (const int*)d_in[2];     // [256,512,9]    int32
    const int*   gj   = (const int*)d_in[3];     // [256,512,9]    int32
    float*       out  = (float*)d_out;           // [8,1,512,1024] fp32

    const size_t bytesD   = (size_t)TAPS * HWn * Bn * sizeof(float); // 37.75 MB
    const size_t bytesOff = (size_t)TAPS * HWn * sizeof(int);        //  4.72 MB

    if (ws_size >= bytesD + bytesOff) {
        float* D    = (float*)d_ws;
        int*   off9 = (int*)((char*)d_ws + bytesD);
        pass0_idx    <<<HWn / 256, 256, 0, stream>>>(gi, gj, off9);
        pass1_chandot<<<HWn / 256, 256, 0, stream>>>(feat, wt, D);
        pass2_gather <<<HWn / 256, 256, 0, stream>>>(D, off9, out);
    } else {
        direct_kernel<<<(Bn * HWn) / 256, 256, 0, stream>>>(feat, wt, gi, gj, out);
    }
}

// Round 4
// 364.851 us; speedup vs baseline: 1.1127x; 1.1127x over previous
//
#include <hip/hip_runtime.h>

// B=8, C=64, H=256, W=512, 3x3 spherical taps, O=1, 2x2 upsample -> (8,1,512,1024) fp32.
#define Bn   8
#define Cn   64
#define Hn   256
#define Wn   512
#define HWn  (Hn * Wn)
#define TAPS 9

typedef float vfloat2 __attribute__((ext_vector_type(2)));  // NT-store-compatible

// ---------------------------------------------------------------------------
// Pass 1: channel-dot, batch-innermost output layout.
//   D[k][p][b] = sum_c feat[b][c][p] * wt[c][k]
// Thread per pixel. Software-pipelined: double-buffered chunks of 4 channels
// (32 nontemporal dword loads in flight) so 8 waves/CU can cover ~900-cycle
// HBM latency. Weights are wave-uniform -> scalar (s_load) reads.
// NT loads keep the 256 MB feature stream from evicting D out of L2/L3.
// ---------------------------------------------------------------------------
__global__ __launch_bounds__(256) void pass1_chandot(
    const float* __restrict__ feat, const float* __restrict__ wt,
    float* __restrict__ D)
{
    const int p = blockIdx.x * 256 + threadIdx.x;   // 0..HW-1

    float acc[TAPS][Bn];
#pragma unroll
    for (int k = 0; k < TAPS; ++k)
#pragma unroll
        for (int b = 0; b < Bn; ++b) acc[k][b] = 0.f;

    float buf[2][4][Bn];                            // 64 VGPRs of stage regs

    // prologue: chunk 0 (c = 0..3)
#pragma unroll
    for (int ci = 0; ci < 4; ++ci)
#pragma unroll
        for (int b = 0; b < Bn; ++b)
            buf[0][ci][b] = __builtin_nontemporal_load(
                feat + (size_t)(b * Cn + ci) * HWn + p);

#pragma unroll
    for (int g = 0; g < 16; ++g) {
        const int cur = g & 1, nxt = cur ^ 1;
        if (g < 15) {                                // prefetch chunk g+1
            const int c0 = (g + 1) * 4;
#pragma unroll
            for (int ci = 0; ci < 4; ++ci)
#pragma unroll
                for (int b = 0; b < Bn; ++b)
                    buf[nxt][ci][b] = __builtin_nontemporal_load(
                        feat + (size_t)(b * Cn + c0 + ci) * HWn + p);
        }
#pragma unroll
        for (int ci = 0; ci < 4; ++ci) {
            const int c = g * 4 + ci;
#pragma unroll
            for (int k = 0; k < TAPS; ++k) {
                const float wv = wt[c * TAPS + k];   // uniform -> SGPR
#pragma unroll
                for (int b = 0; b < Bn; ++b)
                    acc[k][b] = fmaf(buf[cur][ci][b], wv, acc[k][b]);
            }
        }
    }

    // store: D[k][p][b] -- 2 contiguous float4 per tap, wave covers 2 KB.
#pragma unroll
    for (int k = 0; k < TAPS; ++k) {
        float4* dst = (float4*)(D + ((size_t)k * HWn + p) * Bn);
        dst[0] = make_float4(acc[k][0], acc[k][1], acc[k][2], acc[k][3]);
        dst[1] = make_float4(acc[k][4], acc[k][5], acc[k][6], acc[k][7]);
    }
}

// ---------------------------------------------------------------------------
// Pass 2: per block, stage 256 pixels' gi/gj through LDS (coalesced global
// reads; stride-9 LDS reads are conflict-free since gcd(9,32)=1), then gather
// 9 taps x 8 batches (2x float4 = 32 B contiguous per lane) from L2/L3-
// resident D, sum over taps, NT-write the 2x2-upsampled output.
// ---------------------------------------------------------------------------
__global__ __launch_bounds__(256) void pass2_gather(
    const float* __restrict__ D, const int* __restrict__ gi,
    const int* __restrict__ gj, float* __restrict__ out)
{
    __shared__ int loff[256 * TAPS];
    const int tid   = threadIdx.x;
    const int p0    = blockIdx.x * 256;
    const int gbase = p0 * TAPS;

#pragma unroll
    for (int i = tid; i < 256 * TAPS; i += 256)
        loff[i] = gi[gbase + i] * Wn + gj[gbase + i];
    __syncthreads();

    const int p = p0 + tid;
    const int w = p & (Wn - 1);
    const int h = p >> 9;

    float a[Bn];
#pragma unroll
    for (int b = 0; b < Bn; ++b) a[b] = 0.f;

#pragma unroll
    for (int k = 0; k < TAPS; ++k) {
        const int off = loff[tid * TAPS + k];
        const float4* d = (const float4*)(D + ((size_t)k * HWn + off) * Bn);
        float4 d0 = d[0], d1 = d[1];
        a[0] += d0.x; a[1] += d0.y; a[2] += d0.z; a[3] += d0.w;
        a[4] += d1.x; a[5] += d1.y; a[6] += d1.z; a[7] += d1.w;
    }

#pragma unroll
    for (int b = 0; b < Bn; ++b) {
        vfloat2 vv = {a[b], a[b]};
        size_t o = ((size_t)b * (2 * Hn) + 2 * h) * (size_t)(2 * Wn) + 2 * w;
        __builtin_nontemporal_store(vv, (vfloat2*)(out + o));
        __builtin_nontemporal_store(vv, (vfloat2*)(out + o + 2 * Wn));
    }
}

// ---------------------------------------------------------------------------
// Fallback (ws too small): direct per-pixel 9x64 gather-dot.
// ---------------------------------------------------------------------------
__global__ __launch_bounds__(256) void direct_kernel(
    const float* __restrict__ feat, const float* __restrict__ wt,
    const int* __restrict__ gi, const int* __restrict__ gj,
    float* __restrict__ out)
{
    int p = blockIdx.x * blockDim.x + threadIdx.x;
    int w = p & (Wn - 1);
    int h = (p >> 9) & (Hn - 1);
    int b = p >> 17;

    int iidx = ((h << 9) | w) * TAPS;
    int off[TAPS];
#pragma unroll
    for (int k = 0; k < TAPS; ++k)
        off[k] = gi[iidx + k] * Wn + gj[iidx + k];

    float acc = 0.f;
    for (int c = 0; c < Cn; ++c) {
        const float* fc = feat + ((size_t)b * Cn + c) * HWn;
#pragma unroll
        for (int k = 0; k < TAPS; ++k)
            acc = fmaf(fc[off[k]], wt[c * TAPS + k], acc);
    }

    float2 v = make_float2(acc, acc);
    size_t o0 = ((size_t)b * (2 * Hn) + 2 * h) * (size_t)(2 * Wn) + 2 * w;
    *(float2*)(out + o0)          = v;
    *(float2*)(out + o0 + 2 * Wn) = v;
}

extern "C" void kernel_launch(void* const* d_in, const int* in_sizes, int n_in,
                              void* d_out, int out_size, void* d_ws, size_t ws_size,
                              hipStream_t stream) {
    const float* feat = (const float*)d_in[0];   // [8,64,256,512] fp32
    const float* wt   = (const float*)d_in[1];   // [1,64,3,3]     fp32
    const int*   gi   = (const int*)d_in[2];     // [256,512,9]    int32
    const int*   gj   = (const int*)d_in[3];     // [256,512,9]    int32
    float*       out  = (float*)d_out;           // [8,1,512,1024] fp32

    const size_t bytesD = (size_t)TAPS * HWn * Bn * sizeof(float); // 37.75 MB

    if (ws_size >= bytesD) {
        float* D = (float*)d_ws;
        pass1_chandot<<<HWn / 256, 256, 0, stream>>>(feat, wt, D);
        pass2_gather <<<HWn / 256, 256, 0, stream>>>(D, gi, gj, out);
    } else {
        direct_kernel<<<(Bn * HWn) / 256, 256, 0, stream>>>(feat, wt, gi, gj, out);
    }
}